// Round 13
// baseline (1310.530 us; speedup 1.0000x reference)
//
#include <hip/hip_runtime.h>
#include <hip/hip_bf16.h>

#define TOK 8192
#define OUTD 768
#define KD 32768

#define BM 128
#define BN 768                     // full output width: X read exactly once
#define BK 64                      // A-step; B streams from L2 per-fragment
#define SPLITK 8
#define KCHUNK (KD / SPLITK)       // 4096
#define NKT (KCHUNK / BK)          // 64 steps
#define THREADS 512
#define ATILE (BM * BK * 2)        // 16384 B

// ws layout: [0,3072)=negc | W bf16 row-major [col][k] 48MB | partials 200MB
#define WSOFF_W 4096
#define WSOFF_P (WSOFF_W + (long)OUTD * KD * 2)   // 50,335,744
#define PSTRIDE ((long)TOK * OUTD)                // per-ks partial plane

typedef __attribute__((ext_vector_type(4))) float f32x4;
typedef __attribute__((ext_vector_type(16))) float f32x16;
typedef __attribute__((ext_vector_type(8))) short bf16x8;
typedef __attribute__((ext_vector_type(4))) unsigned int u32x4;

__device__ __forceinline__ unsigned pack2(float lo, float hi) {
    __hip_bfloat162 h = __float22bfloat162_rn(make_float2(lo, hi));
    unsigned u;
    __builtin_memcpy(&u, &h, 4);
    return u;
}

__device__ __forceinline__ u32x4 cvt_chunk(f32x4 a, f32x4 b) {
    u32x4 r;
    r[0] = pack2(a[0], a[1]);
    r[1] = pack2(a[2], a[3]);
    r[2] = pack2(b[0], b[1]);
    r[3] = pack2(b[2], b[3]);
    return r;
}

// ---------------------------------------------------------------------------
// Kernel 0: negc[o] = -dot(W[o,:], b_pre)   (rank-1 bias correction)
// ---------------------------------------------------------------------------
__global__ void colbias_kernel(const float* __restrict__ W,
                               const float* __restrict__ bp,
                               float* __restrict__ negc) {
    int o = blockIdx.x;
    int tid = threadIdx.x;  // 256
    const float* wr = W + (long)o * KD;
    float s = 0.f;
    for (int i = tid * 4; i < KD; i += 256 * 4) {
        f32x4 w = *(const f32x4*)(wr + i);
        f32x4 b = *(const f32x4*)(bp + i);
        s += w[0] * b[0] + w[1] * b[1] + w[2] * b[2] + w[3] * b[3];
    }
    #pragma unroll
    for (int off = 32; off > 0; off >>= 1) s += __shfl_down(s, off);
    __shared__ float red[4];
    if ((tid & 63) == 0) red[tid >> 6] = s;
    __syncthreads();
    if (tid == 0) negc[o] = -(red[0] + red[1] + red[2] + red[3]);
}

// ---------------------------------------------------------------------------
// Kernel 1: cast W f32 -> bf16 row-major [col 0..767][k 0..32767] in ws.
// A B-fragment (8 k-contiguous bf16) is then one aligned b128 load.
// ---------------------------------------------------------------------------
__global__ void cast_w_kernel(const float* __restrict__ W,
                              char* __restrict__ wsW) {
    int col = blockIdx.x;    // 0..767
    int tid = threadIdx.x;   // 256
    const float* src = W + (long)col * KD;
    char* dst = wsW + (long)col * KD * 2;
    #pragma unroll
    for (int i = 0; i < 16; ++i) {
        int k = (tid + i * 256) * 8;
        f32x4 a = *(const f32x4*)(src + k);
        f32x4 b = *(const f32x4*)(src + k + 4);
        *(u32x4*)(dst + k * 2) = cvt_chunk(a, b);
    }
}

// ---------------------------------------------------------------------------
// Kernel 2: split-K bf16 GEMM, 128 rows x FULL 768 cols per block.
//   A (x f32): reg-prefetch -> cvt -> 8-octet-swizzled LDS, dbuf, BK=64,
//              ONE __syncthreads per step (32 KB LDS total).
//   B (W bf16): NO LDS — fragments loaded b128 directly from the row-major
//              ws image. ks = bid&7 pins one 6MB W-chunk per XCD -> L2-
//              resident; every 128B line fully consumed within the step.
//   Compiler schedules B-loads ∥ MFMA (implicit wave overlap, m114).
// ---------------------------------------------------------------------------
__global__ __launch_bounds__(THREADS, 2) void decoder_gemm(
    const float* __restrict__ X, const char* __restrict__ Wb,
    float* __restrict__ P) {
    __shared__ char ldsA[2 * ATILE];  // 32 KB

    const int bid = blockIdx.x;         // 512 blocks; ks fastest -> ks==XCD
    const int ks = bid & (SPLITK - 1);
    const int mt = bid >> 3;            // 0..63
    const int row0 = mt * BM;

    const int tid = threadIdx.x;
    const int lane = tid & 63;
    const int wid = tid >> 6;
    const int wm = wid >> 2;   // 0..1 -> 64-row half
    const int wn = wid & 3;    // 0..3 -> 192-col quarter
    const int l31 = lane & 31;
    const int hi = lane >> 5;

    const float* Xb = X + (long)row0 * KD + (long)ks * KCHUNK;

    // B fragment base pointers (byte): col-major-row image, k advances 2B
    const char* bptr[6];
    #pragma unroll
    for (int n = 0; n < 6; ++n) {
        int col = wn * 192 + n * 32 + l31;
        bptr[n] = Wb + ((long)col * KD + (long)ks * KCHUNK) * 2 + hi * 16;
    }

    // A staging: 512 thr = 128 rows x 4 k-chunks of 16 f32
    const int ar = tid >> 2;   // 0..127
    const int aq = tid & 3;    // 16-f32 chunk (octets aq*2, aq*2+1)
    f32x4 xr[4];

    auto LOADA = [&](int kt) {
        const f32x4* p = (const f32x4*)(Xb + (long)ar * KD + kt * 64 + aq * 16);
        xr[0] = p[0];
        xr[1] = p[1];
        xr[2] = p[2];
        xr[3] = p[3];
    };

    // A layout: byte = row*128 + slot*16, slot = octet ^ (row&7)  (octet=k>>3)
    const int soff1 = ar * 128 + (((aq * 2) ^ (ar & 7)) << 4);
    const int soff2 = ar * 128 + (((aq * 2 + 1) ^ (ar & 7)) << 4);

    auto STOREA = [&](int buf) {
        char* base = ldsA + buf * ATILE;
        *(u32x4*)(base + soff1) = cvt_chunk(xr[0], xr[1]);
        *(u32x4*)(base + soff2) = cvt_chunk(xr[2], xr[3]);
    };

    // A fragment address pieces: row = wm*64 + m*32 + l31
    int arow[2], arx[2];
    #pragma unroll
    for (int m = 0; m < 2; ++m) {
        int row = wm * 64 + m * 32 + l31;
        arow[m] = row * 128;
        arx[m] = row & 7;
    }

    f32x16 acc[2][6];
    #pragma unroll
    for (int m = 0; m < 2; ++m)
        #pragma unroll
        for (int n = 0; n < 6; ++n)
            #pragma unroll
            for (int r = 0; r < 16; ++r) acc[m][n][r] = 0.f;

    auto COMPUTE = [&](int buf, int kt) {
        const char* base = ldsA + buf * ATILE;
        #pragma unroll
        for (int kk = 0; kk < 4; ++kk) {
            bf16x8 bfr[6], afr[2];
            #pragma unroll
            for (int n = 0; n < 6; ++n)
                bfr[n] = *(const bf16x8*)(bptr[n] + kt * 128 + kk * 32);
            #pragma unroll
            for (int m = 0; m < 2; ++m) {
                int oct = kk * 2 + hi;
                afr[m] = *(const bf16x8*)(base + arow[m] +
                                          ((oct ^ arx[m]) << 4));
            }
            __builtin_amdgcn_s_setprio(1);
            #pragma unroll
            for (int m = 0; m < 2; ++m)
                #pragma unroll
                for (int n = 0; n < 6; ++n)
                    acc[m][n] = __builtin_amdgcn_mfma_f32_32x32x16_bf16(
                        afr[m], bfr[n], acc[m][n], 0, 0, 0);
            __builtin_amdgcn_s_setprio(0);
        }
    };

    // prologue
    LOADA(0);
    STOREA(0);
    __syncthreads();

    for (int kt = 0; kt < NKT; ++kt) {
        const int cur = kt & 1;
        const bool more = (kt + 1 < NKT);
        if (more) LOADA(kt + 1);   // X loads in flight under the whole step
        COMPUTE(cur, kt);
        if (more) STOREA(cur ^ 1); // counted wait on own loads; other buffer
        __syncthreads();           // publish A(kt+1)
    }

    // epilogue: plain coalesced stores of this ks-partial.
    // 32x32 C/D layout: col=lane&31, row=(r&3)+8*(r>>2)+4*(lane>>5)
    float* Pk = P + (long)ks * PSTRIDE;
    #pragma unroll
    for (int m = 0; m < 2; ++m) {
        int rowb = row0 + wm * 64 + m * 32 + 4 * hi;
        #pragma unroll
        for (int n = 0; n < 6; ++n) {
            int col = wn * 192 + n * 32 + l31;
            #pragma unroll
            for (int r = 0; r < 16; ++r) {
                int row = rowb + (r & 3) + 8 * (r >> 2);
                Pk[(long)row * OUTD + col] = acc[m][n][r];
            }
        }
    }
}

// ---------------------------------------------------------------------------
// Kernel 3: out = sum_ks partial[ks] + negc[col]
// ---------------------------------------------------------------------------
__global__ void reduce_kernel(const float* __restrict__ P,
                              const float* __restrict__ negc,
                              float* __restrict__ out) {
    long i4 = ((long)blockIdx.x * blockDim.x + threadIdx.x) * 4;
    int col = (int)(i4 % OUTD);
    f32x4 s = *(const f32x4*)(negc + col);
    #pragma unroll
    for (int ks = 0; ks < SPLITK; ++ks)
        s += *(const f32x4*)(P + ks * PSTRIDE + i4);
    *(f32x4*)(out + i4) = s;
}

// ---------------------------------------------------------------------------
extern "C" void kernel_launch(void* const* d_in, const int* in_sizes, int n_in,
                              void* d_out, int out_size, void* d_ws,
                              size_t ws_size, hipStream_t stream) {
    const float* x = (const float*)d_in[0];
    const float* W = (const float*)d_in[1];
    const float* bp = (const float*)d_in[2];
    float* out = (float*)d_out;
    float* negc = (float*)d_ws;
    char* wsW = (char*)d_ws + WSOFF_W;
    float* wsP = (float*)((char*)d_ws + WSOFF_P);
    // ws need: ~252 MB (harness 0xAA fill = 4.3 GB, rounds 6-12)

    hipLaunchKernelGGL(colbias_kernel, dim3(OUTD), dim3(256), 0, stream, W, bp,
                       negc);
    hipLaunchKernelGGL(cast_w_kernel, dim3(OUTD), dim3(256), 0, stream, W,
                       wsW);
    hipLaunchKernelGGL(decoder_gemm, dim3((TOK / BM) * SPLITK), dim3(THREADS),
                       0, stream, x, wsW, wsP);
    hipLaunchKernelGGL(reduce_kernel, dim3((TOK * OUTD) / (256 * 4)), dim3(256),
                       0, stream, wsP, negc, out);
}

// Round 14
// 644.415 us; speedup vs baseline: 2.0337x; 2.0337x over previous
//
#include <hip/hip_runtime.h>
#include <hip/hip_bf16.h>

#define TOK 8192
#define OUTD 768
#define KD 32768

#define BM 128
#define BN 768                     // full output width: X read exactly once
#define BK 32
#define SPLITK 4
#define KCHUNK (KD / SPLITK)       // 8192
#define NKT (KCHUNK / BK)          // 256 steps
#define NHT_TOT (KD / BK)          // 1024 32-k tiles of W
#define THREADS 512
#define HTILE (BN * BK * 2)        // 49152 B (48KB swizzled W tile image)
#define ATILE (BM * BK * 2)        // 8192 B
#define WBUF 6144                  // per-wave per-step B slice (96 cols x 64B)

// ws layout: [0,3072)=negc | 4096 + 48MB W image | partials 100MB
#define WSOFF_W 4096
#define WSOFF_P (WSOFF_W + (long)NHT_TOT * HTILE)   // 50,335,744
#define PSTRIDE ((long)TOK * OUTD)                  // per-ks partial plane

typedef __attribute__((ext_vector_type(4))) float f32x4;
typedef __attribute__((ext_vector_type(16))) float f32x16;
typedef __attribute__((ext_vector_type(8))) short bf16x8;
typedef __attribute__((ext_vector_type(4))) unsigned int u32x4;

__device__ __forceinline__ unsigned pack2(float lo, float hi) {
    __hip_bfloat162 h = __float22bfloat162_rn(make_float2(lo, hi));
    unsigned u;
    __builtin_memcpy(&u, &h, 4);
    return u;
}

__device__ __forceinline__ u32x4 cvt_chunk(f32x4 a, f32x4 b) {
    u32x4 r;
    r[0] = pack2(a[0], a[1]);
    r[1] = pack2(a[2], a[3]);
    r[2] = pack2(b[0], b[1]);
    r[3] = pack2(b[2], b[3]);
    return r;
}

// ---------------------------------------------------------------------------
// Kernel 0: negc[o] = -dot(W[o,:], b_pre)   (rank-1 bias correction)
// ---------------------------------------------------------------------------
__global__ void colbias_kernel(const float* __restrict__ W,
                               const float* __restrict__ bp,
                               float* __restrict__ negc) {
    int o = blockIdx.x;
    int tid = threadIdx.x;  // 256
    const float* wr = W + (long)o * KD;
    float s = 0.f;
    for (int i = tid * 4; i < KD; i += 256 * 4) {
        f32x4 w = *(const f32x4*)(wr + i);
        f32x4 b = *(const f32x4*)(bp + i);
        s += w[0] * b[0] + w[1] * b[1] + w[2] * b[2] + w[3] * b[3];
    }
    #pragma unroll
    for (int off = 32; off > 0; off >>= 1) s += __shfl_down(s, off);
    __shared__ float red[4];
    if ((tid & 63) == 0) red[tid >> 6] = s;
    __syncthreads();
    if (tid == 0) negc[o] = -(red[0] + red[1] + red[2] + red[3]);
}

// ---------------------------------------------------------------------------
// Kernel 1: cast W f32 -> bf16 into ws as 1024 swizzled 48KB tile images
// (byte-exact r11 layout: byte = col*64 + ((octet ^ (col&3))<<4)).
// ---------------------------------------------------------------------------
__global__ void cast_w_kernel(const float* __restrict__ W,
                              char* __restrict__ wsW) {
    int kth = blockIdx.x;    // 0..1023, 32-k tile index
    int tid = threadIdx.x;   // 512
    int q = tid & 3;         // k-octet
    int c0 = tid >> 2;       // 0..127
    #pragma unroll
    for (int i = 0; i < 6; ++i) {
        int c = c0 + i * 128;  // 0..767
        const float* src = W + (long)c * KD + kth * 32 + q * 8;
        f32x4 a = ((const f32x4*)src)[0];
        f32x4 b = ((const f32x4*)src)[1];
        char* dst = wsW + (long)kth * HTILE + c * 64 + ((q ^ (c & 3)) << 4);
        *(u32x4*)dst = cvt_chunk(a, b);
    }
}

// ---------------------------------------------------------------------------
// Kernel 2: split-K bf16 GEMM, 1M x 8N wave decomposition.
// Each wave: all 128 rows x a PRIVATE 96-col slice. B is wave-private:
// the wave DMAs its own 6KB slice (tri-buffered), waits with per-wave
// counted vmcnt — B never crosses a barrier, never drains to 0.
// A (8KB, shared): reg-staged dbuf; ONE raw s_barrier per step with
// lgkmcnt(0) only (no vmcnt drain).
// vm-queue ledger (steady): top = B(kt+1)x6; +A(kt+1)x2 +B(kt+2)x6 = 14;
// vmcnt(8) drains B(kt+1); STOREA auto-vmcnt(6) leaves B(kt+2) in flight.
// ---------------------------------------------------------------------------
__global__ __launch_bounds__(THREADS, 1) void decoder_gemm(
    const float* __restrict__ X, const char* __restrict__ Wb16,
    float* __restrict__ P) {
    __shared__ char lds[2 * ATILE + 24 * WBUF];  // A:16KB | B:8 waves x 3 x 6KB
    char* ldsA = lds;
    char* ldsB = lds + 2 * ATILE;

    const int bid = blockIdx.x;     // 256 blocks; ks fastest
    const int ks = bid & (SPLITK - 1);
    const int mt = bid >> 2;
    const int row0 = mt * BM;

    const int tid = threadIdx.x;
    const int lane = tid & 63;
    const int wid = tid >> 6;   // 0..7: owns cols [wid*96, wid*96+96)
    const int l31 = lane & 31;
    const int hi = lane >> 5;

    const float* Xb = X + (long)row0 * KD + (long)ks * KCHUNK;
    const char* Wt0 = Wb16 + (long)ks * NKT * HTILE + wid * WBUF;
    char* myB = ldsB + wid * 3 * WBUF;

    // A staging: thread -> (row ar, k-octet aq); 512 = 128 rows x 4 octets
    const int ar = tid >> 2;   // 0..127
    const int aq = tid & 3;
    f32x4 xr[2];

    auto LOADA = [&](int kt) {
        const f32x4* p = (const f32x4*)(Xb + (long)ar * KD + kt * 32 + aq * 8);
        xr[0] = p[0];
        xr[1] = p[1];
    };

    const int asoff = ar * 64 + ((aq ^ (ar & 3)) << 4);

    auto STOREA = [&](int buf) {
        *(u32x4*)(ldsA + buf * ATILE + asoff) = cvt_chunk(xr[0], xr[1]);
    };

    auto ISSUEB = [&](int kt, int buf) {
        const char* src = Wt0 + (long)kt * HTILE + lane * 16;
        char* dst = myB + buf * WBUF + lane * 16;
        #pragma unroll
        for (int j = 0; j < 6; ++j)
            __builtin_amdgcn_global_load_lds(
                (const __attribute__((address_space(1))) void*)(src + j * 1024),
                (__attribute__((address_space(3))) void*)(dst + j * 1024),
                16, 0, 0);
    };

    // fragment offsets (r11 swizzle): slot = (kk*2+hi) ^ (c&3), kk -> ^ (kk<<5)
    int aoff[4], boff[3];
    #pragma unroll
    for (int m = 0; m < 4; ++m) {
        int row = m * 32 + l31;
        aoff[m] = row * 64 + ((hi ^ (row & 3)) << 4);
    }
    #pragma unroll
    for (int n = 0; n < 3; ++n) {
        int c = n * 32 + l31;  // col within private slice
        boff[n] = c * 64 + ((hi ^ (c & 3)) << 4);
    }

    f32x16 acc[4][3];
    #pragma unroll
    for (int m = 0; m < 4; ++m)
        #pragma unroll
        for (int n = 0; n < 3; ++n)
            #pragma unroll
            for (int r = 0; r < 16; ++r) acc[m][n][r] = 0.f;

    auto COMPUTE = [&](int b3, int abuf) {
        const char* As = ldsA + abuf * ATILE;
        const char* Bs = myB + b3 * WBUF;
        #pragma unroll
        for (int kk = 0; kk < 2; ++kk) {
            bf16x8 afr[4], bfr[3];
            #pragma unroll
            for (int n = 0; n < 3; ++n)
                bfr[n] = *(const bf16x8*)(Bs + (boff[n] ^ (kk << 5)));
            #pragma unroll
            for (int m = 0; m < 4; ++m)
                afr[m] = *(const bf16x8*)(As + (aoff[m] ^ (kk << 5)));
            __builtin_amdgcn_s_setprio(1);
            #pragma unroll
            for (int m = 0; m < 4; ++m)
                #pragma unroll
                for (int n = 0; n < 3; ++n)
                    acc[m][n] = __builtin_amdgcn_mfma_f32_32x32x16_bf16(
                        afr[m], bfr[n], acc[m][n], 0, 0, 0);
            __builtin_amdgcn_s_setprio(0);
        }
    };

    // prologue: A(0) staged, B(0) landed, B(1) in flight
    LOADA(0);          // 2 ops (oldest)
    ISSUEB(0, 0);      // +6 -> 8
    STOREA(0);         // compiler vmcnt(6): drains A(0), leaves B(0)
    ISSUEB(1, 1);      // -> [B0 x6, B1 x6]
    asm volatile("s_waitcnt vmcnt(6) lgkmcnt(0)" ::: "memory");  // B0 done
    __builtin_amdgcn_sched_barrier(0);
    __builtin_amdgcn_s_barrier();

    // steady: top invariant = outstanding B(kt+1) x6; A(kt)+B(kt) resident
    for (int kt = 0; kt < NKT - 2; ++kt) {
        LOADA(kt + 1);                    // +2 (A older than new B)
        ISSUEB(kt + 2, (kt + 2) % 3);     // +6 -> 14
        asm volatile("s_waitcnt vmcnt(8)" ::: "memory");  // B(kt+1) landed
        __builtin_amdgcn_sched_barrier(0);
        COMPUTE(kt % 3, kt & 1);
        STOREA((kt + 1) & 1);             // auto vmcnt(6): B(kt+2) stays out
        asm volatile("s_waitcnt lgkmcnt(0)" ::: "memory");
        __builtin_amdgcn_sched_barrier(0);
        __builtin_amdgcn_s_barrier();     // publish A(kt+1); NO vmcnt drain
    }

    // step NKT-2: last A prefetch, drain B(NKT-1)
    LOADA(NKT - 1);
    asm volatile("s_waitcnt vmcnt(2)" ::: "memory");
    __builtin_amdgcn_sched_barrier(0);
    COMPUTE((NKT - 2) % 3, (NKT - 2) & 1);
    STOREA((NKT - 1) & 1);
    asm volatile("s_waitcnt lgkmcnt(0)" ::: "memory");
    __builtin_amdgcn_sched_barrier(0);
    __builtin_amdgcn_s_barrier();

    // step NKT-1
    COMPUTE((NKT - 1) % 3, (NKT - 1) & 1);

    // epilogue: plain coalesced stores of this ks-partial.
    // 32x32 C/D layout: col=lane&31, row=(r&3)+8*(r>>2)+4*(lane>>5)
    float* Pk = P + (long)ks * PSTRIDE;
    #pragma unroll
    for (int m = 0; m < 4; ++m) {
        int rowb = row0 + m * 32 + 4 * hi;
        #pragma unroll
        for (int n = 0; n < 3; ++n) {
            int col = wid * 96 + n * 32 + l31;
            #pragma unroll
            for (int r = 0; r < 16; ++r) {
                int row = rowb + (r & 3) + 8 * (r >> 2);
                Pk[(long)row * OUTD + col] = acc[m][n][r];
            }
        }
    }
}

// ---------------------------------------------------------------------------
// Kernel 3: out = sum_ks partial[ks] + negc[col]
// ---------------------------------------------------------------------------
__global__ void reduce_kernel(const float* __restrict__ P,
                              const float* __restrict__ negc,
                              float* __restrict__ out) {
    long i4 = ((long)blockIdx.x * blockDim.x + threadIdx.x) * 4;
    int col = (int)(i4 % OUTD);
    f32x4 s = *(const f32x4*)(negc + col);
    #pragma unroll
    for (int ks = 0; ks < SPLITK; ++ks)
        s += *(const f32x4*)(P + ks * PSTRIDE + i4);
    *(f32x4*)(out + i4) = s;
}

// ---------------------------------------------------------------------------
extern "C" void kernel_launch(void* const* d_in, const int* in_sizes, int n_in,
                              void* d_out, int out_size, void* d_ws,
                              size_t ws_size, hipStream_t stream) {
    const float* x = (const float*)d_in[0];
    const float* W = (const float*)d_in[1];
    const float* bp = (const float*)d_in[2];
    float* out = (float*)d_out;
    float* negc = (float*)d_ws;
    char* wsW = (char*)d_ws + WSOFF_W;
    float* wsP = (float*)((char*)d_ws + WSOFF_P);

    hipLaunchKernelGGL(colbias_kernel, dim3(OUTD), dim3(256), 0, stream, W, bp,
                       negc);
    hipLaunchKernelGGL(cast_w_kernel, dim3(NHT_TOT), dim3(512), 0, stream, W,
                       wsW);
    hipLaunchKernelGGL(decoder_gemm, dim3((TOK / BM) * SPLITK), dim3(THREADS),
                       0, stream, x, wsW, wsP);
    hipLaunchKernelGGL(reduce_kernel, dim3((TOK * OUTD) / (256 * 4)), dim3(256),
                       0, stream, wsP, negc, out);
}